// Round 14
// baseline (468.533 us; speedup 1.0000x reference)
//
#include <hip/hip_runtime.h>
#include <stdint.h>

#define NSEQ 64      // B*C
#define TT   256
#define FF   64
#define DM   128
#define DI   256
#define DS   16
#define DTR  8
#define XDBL 40      // DTR + 2*DS
#define CH   32      // scan chunk length
#define NCH  (TT / CH)
#define LN_EPS 1e-5f

__device__ __forceinline__ float silu(float v) { return v / (1.f + __expf(-v)); }

// ============ kernel 1: input projection GEMM ============
// LDS strides 65/131 (odd): scatter-staging writes spread over all 32 banks
__global__ __launch_bounds__(256) void k_input_proj(const float* __restrict__ x,
                                                    const float* __restrict__ w,
                                                    const float* __restrict__ b,
                                                    float* __restrict__ h) {
    __shared__ float As[FF][65];    // As[f][local_t]
    __shared__ float Bs[FF][131];   // Bs[f][dm]
    const int m0 = blockIdx.x * 64;
    const int n = m0 >> 8, t0 = m0 & 255;
    const int tid = threadIdx.x;
    {
        const int tq = tid & 15, f0 = tid >> 4;
#pragma unroll
        for (int i = 0; i < 4; ++i) {
            int f = f0 + 16 * i;
            float4 v = *(const float4*)&x[((size_t)n * FF + f) * TT + t0 + 4 * tq];
            *(float4*)&As[f][4 * tq] = v;
        }
#pragma unroll
        for (int i = 0; i < 8; ++i) {
            int col = f0 + 16 * i;
            float4 v = *(const float4*)&w[(size_t)col * FF + 4 * tq];
            Bs[4 * tq + 0][col] = v.x; Bs[4 * tq + 1][col] = v.y;
            Bs[4 * tq + 2][col] = v.z; Bs[4 * tq + 3][col] = v.w;
        }
    }
    __syncthreads();
    const int ty = tid >> 4, tx = tid & 15;
    float acc[4][8];
#pragma unroll
    for (int r = 0; r < 4; ++r)
#pragma unroll
        for (int c = 0; c < 8; ++c) acc[r][c] = 0.f;
#pragma unroll 8
    for (int k = 0; k < FF; ++k) {
        float4 a = *(float4*)&As[k][ty * 4];
        float4 b0 = *(float4*)&Bs[k][tx * 8];
        float4 b1 = *(float4*)&Bs[k][tx * 8 + 4];
        float av[4] = {a.x, a.y, a.z, a.w};
        float bv[8] = {b0.x, b0.y, b0.z, b0.w, b1.x, b1.y, b1.z, b1.w};
#pragma unroll
        for (int r = 0; r < 4; ++r)
#pragma unroll
            for (int c = 0; c < 8; ++c) acc[r][c] += av[r] * bv[c];
    }
#pragma unroll
    for (int r = 0; r < 4; ++r) {
        int row = m0 + ty * 4 + r;
        float4 o0, o1;
        o0.x = acc[r][0] + b[tx * 8 + 0]; o0.y = acc[r][1] + b[tx * 8 + 1];
        o0.z = acc[r][2] + b[tx * 8 + 2]; o0.w = acc[r][3] + b[tx * 8 + 3];
        o1.x = acc[r][4] + b[tx * 8 + 4]; o1.y = acc[r][5] + b[tx * 8 + 5];
        o1.z = acc[r][6] + b[tx * 8 + 6]; o1.w = acc[r][7] + b[tx * 8 + 7];
        *(float4*)&h[(size_t)row * DM + tx * 8] = o0;
        *(float4*)&h[(size_t)row * DM + tx * 8 + 4] = o1;
    }
}

// ============ kernel 2: in_proj GEMM (LDS stride 65 kills 8-way staging conflict) ====
__global__ __launch_bounds__(256) void k_in_proj(const float* __restrict__ h,
                                                 const float* __restrict__ ipw,
                                                 float* __restrict__ xz, int l) {
    __shared__ float As[64][65];
    __shared__ float Bs[64][65];
    const int m0 = (blockIdx.x >> 3) * 64;
    const int n0 = (blockIdx.x & 7) * 64;
    const int tid = threadIdx.x;
    const int ty = tid >> 4, tx = tid & 15;
    const float* wbase = ipw + (size_t)l * 2 * DI * DM;
    float acc[4][4];
#pragma unroll
    for (int r = 0; r < 4; ++r)
#pragma unroll
        for (int c = 0; c < 4; ++c) acc[r][c] = 0.f;

    for (int k0 = 0; k0 < DM; k0 += 64) {
        const int kq = tid & 15, r0 = tid >> 4;
#pragma unroll
        for (int i = 0; i < 4; ++i) {
            int row = r0 + 16 * i;
            float4 v = *(const float4*)&h[(size_t)(m0 + row) * DM + k0 + 4 * kq];
            As[4 * kq + 0][row] = v.x; As[4 * kq + 1][row] = v.y;
            As[4 * kq + 2][row] = v.z; As[4 * kq + 3][row] = v.w;
            float4 wv = *(const float4*)&wbase[(size_t)(n0 + row) * DM + k0 + 4 * kq];
            Bs[4 * kq + 0][row] = wv.x; Bs[4 * kq + 1][row] = wv.y;
            Bs[4 * kq + 2][row] = wv.z; Bs[4 * kq + 3][row] = wv.w;
        }
        __syncthreads();
#pragma unroll 8
        for (int k = 0; k < 64; ++k) {
            float4 a = *(float4*)&As[k][ty * 4];
            float4 b = *(float4*)&Bs[k][tx * 4];
            float av[4] = {a.x, a.y, a.z, a.w};
            float bv[4] = {b.x, b.y, b.z, b.w};
#pragma unroll
            for (int r = 0; r < 4; ++r)
#pragma unroll
                for (int c = 0; c < 4; ++c) acc[r][c] += av[r] * bv[c];
        }
        __syncthreads();
    }
#pragma unroll
    for (int r = 0; r < 4; ++r) {
        int row = m0 + ty * 4 + r;
        float4 o = {acc[r][0], acc[r][1], acc[r][2], acc[r][3]};
        *(float4*)&xz[(size_t)row * (2 * DI) + n0 + tx * 4] = o;
    }
}

// ============ kernel 3: causal depthwise conv + silu -> u ============
__global__ __launch_bounds__(256) void k_conv(const float* __restrict__ xz,
                                              const float* __restrict__ cw,
                                              const float* __restrict__ cb,
                                              float* __restrict__ u, int l) {
    int idx = blockIdx.x * 256 + threadIdx.x;
    int d = idx & (DI - 1);
    int nt = idx >> 8;
    int t = nt & 255;
    const float* wr = cw + ((size_t)l * DI + d) * 4;
    float acc = cb[l * DI + d];
#pragma unroll
    for (int j = 0; j < 4; ++j) {
        int back = 3 - j;
        if (t - back >= 0)
            acc += xz[(size_t)(nt - back) * (2 * DI) + d] * wr[j];
    }
    u[(size_t)nt * DI + d] = silu(acc);
}

// ============ kernel 4: x_dbl GEMM, K-split x2, full-K LDS stage + fused delta ======
__global__ __launch_bounds__(512) void k_xd(const float* __restrict__ u,
                                            const float* __restrict__ xpw,
                                            const float* __restrict__ dtw,
                                            const float* __restrict__ dtb,
                                            float* __restrict__ xdbl,
                                            float* __restrict__ xz, int l) {
    __shared__ float As[64][260];
    __shared__ float Bs[XDBL][260];
    __shared__ float xdS[64][41];
    const int m0 = blockIdx.x * 64;
    const int tid = threadIdx.x;
    const int hk = tid >> 8;         // K-half
    const int t2 = tid & 255;
    const int ty = t2 >> 3;
    const int tx = t2 & 7;
    for (int i = tid; i < 64 * 64; i += 512) {
        int r = i >> 6, c = (i & 63) * 4;
        *(float4*)&As[r][c] = *(const float4*)&u[(size_t)(m0 + r) * DI + c];
    }
    const float* wbase = xpw + (size_t)l * XDBL * DI;
    for (int i = tid; i < XDBL * 64; i += 512) {
        int r = i >> 6, c = (i & 63) * 4;
        *(float4*)&Bs[r][c] = *(const float4*)&wbase[(size_t)r * DI + c];
    }
    __syncthreads();
    float acc[2][5];
#pragma unroll
    for (int r = 0; r < 2; ++r)
#pragma unroll
        for (int c = 0; c < 5; ++c) acc[r][c] = 0.f;
    const int kbase = hk * 128;
#pragma unroll 4
    for (int kk = 0; kk < 128; kk += 4) {
        const int k = kbase + kk;
        float4 a0 = *(float4*)&As[2 * ty][k];
        float4 a1 = *(float4*)&As[2 * ty + 1][k];
        float4 b[5];
#pragma unroll
        for (int c = 0; c < 5; ++c) b[c] = *(float4*)&Bs[5 * tx + c][k];
#pragma unroll
        for (int c = 0; c < 5; ++c) {
            acc[0][c] += a0.x * b[c].x + a0.y * b[c].y + a0.z * b[c].z + a0.w * b[c].w;
            acc[1][c] += a1.x * b[c].x + a1.y * b[c].y + a1.z * b[c].z + a1.w * b[c].w;
        }
    }
    if (hk == 0) {
#pragma unroll
        for (int r = 0; r < 2; ++r)
#pragma unroll
            for (int c = 0; c < 5; ++c) xdS[2 * ty + r][5 * tx + c] = acc[r][c];
    }
    __syncthreads();
    if (hk == 1) {
#pragma unroll
        for (int r = 0; r < 2; ++r)
#pragma unroll
            for (int c = 0; c < 5; ++c) {
                int m = 2 * ty + r, col = 5 * tx + c;
                float v = xdS[m][col] + acc[r][c];
                xdS[m][col] = v;
                xdbl[(size_t)(m0 + m) * XDBL + col] = v;
            }
    }
    __syncthreads();
    {
        const int ch = tid & 255;
        const int tk0 = hk * 32;
        float4 dw0 = *(const float4*)&dtw[((size_t)l * DI + ch) * DTR];
        float4 dw1 = *(const float4*)&dtw[((size_t)l * DI + ch) * DTR + 4];
        const float bias = dtb[l * DI + ch];
#pragma unroll 8
        for (int tk = tk0; tk < tk0 + 32; ++tk) {
            const float* xr = xdS[tk];
            float a = bias + xr[0] * dw0.x + xr[1] * dw0.y + xr[2] * dw0.z + xr[3] * dw0.w
                           + xr[4] * dw1.x + xr[5] * dw1.y + xr[6] * dw1.z + xr[7] * dw1.w;
            float sp = (a > 20.f) ? a : log1pf(__expf(a));
            xz[(size_t)(m0 + tk) * (2 * DI) + ch] = sp;
        }
    }
}

// ============ kernel 5a: chunked scan pass 1 — local states + delta sums ============
__global__ __launch_bounds__(256) void k_scan1(const float* __restrict__ xz,
                                               const float* __restrict__ u,
                                               const float* __restrict__ xdbl,
                                               const float* __restrict__ alog,
                                               float* __restrict__ hloc,
                                               float* __restrict__ Sbuf, int l) {
    const int n = blockIdx.x >> 5;
    const int c = (blockIdx.x >> 2) & 7;
    const int q = blockIdx.x & 3;
    const int tid = threadIdx.x;
    const int ch = tid >> 2, sg = tid & 3;
    const int d = q * 64 + ch;
    __shared__ float Bs[CH * DS];
    if (tid < 128) {
        int t = tid >> 2, sq = tid & 3;
        const float* row = xdbl + ((size_t)n * TT + c * CH + t) * XDBL;
        *(float4*)&Bs[t * DS + 4 * sq] = *(const float4*)&row[DTR + 4 * sq];
    }
    __syncthreads();
    float4 av = *(const float4*)&alog[((size_t)l * DI + d) * DS + sg * 4];
    float A[4] = {-__expf(av.x), -__expf(av.y), -__expf(av.z), -__expf(av.w)};
    float hst[4] = {0.f, 0.f, 0.f, 0.f};
    float S = 0.f;

    const float* dlt_p = xz + ((size_t)n * TT + c * CH) * (2 * DI) + d;
    const float* uv_p  = u + ((size_t)n * TT + c * CH) * DI + d;
    float pD[16], pU[16];
#pragma unroll
    for (int j = 0; j < 16; ++j) {
        pD[j] = dlt_p[(size_t)j * (2 * DI)];
        pU[j] = uv_p[(size_t)j * DI];
    }
    for (int g = 0; g < 2; ++g) {
        float cD[16], cU[16];
#pragma unroll
        for (int j = 0; j < 16; ++j) { cD[j] = pD[j]; cU[j] = pU[j]; }
        if (g == 0) {
#pragma unroll
            for (int j = 0; j < 16; ++j) {
                pD[j] = dlt_p[(size_t)(16 + j) * (2 * DI)];
                pU[j] = uv_p[(size_t)(16 + j) * DI];
            }
        }
#pragma unroll
        for (int j = 0; j < 16; ++j) {
            const int t = g * 16 + j;
            float dlt = cD[j];
            float du = dlt * cU[j];
            const float* bt = Bs + t * DS + sg * 4;
            S += dlt;
#pragma unroll
            for (int s = 0; s < 4; ++s) {
                float dA = __expf(dlt * A[s]);
                hst[s] = dA * hst[s] + du * bt[s];
            }
        }
    }
    size_t idx = ((((size_t)n * NCH + c) * 4 + q) * 256 + tid);
    float4 hv = {hst[0], hst[1], hst[2], hst[3]};
    *(float4*)&hloc[idx * 4] = hv;
    if (sg == 0) Sbuf[(((size_t)n * NCH + c) * 4 + q) * 64 + ch] = S;
}

// ============ kernel 5b: stitch — serial prefix over chunks, hloc := h_in ============
__global__ __launch_bounds__(256) void k_stitch(float* __restrict__ hloc,
                                                const float* __restrict__ Sbuf,
                                                const float* __restrict__ alog, int l) {
    const int n = blockIdx.x >> 2;
    const int q = blockIdx.x & 3;
    const int tid = threadIdx.x;
    const int ch = tid >> 2, sg = tid & 3;
    const int d = q * 64 + ch;
    float4 av = *(const float4*)&alog[((size_t)l * DI + d) * DS + sg * 4];
    float A[4] = {-__expf(av.x), -__expf(av.y), -__expf(av.z), -__expf(av.w)};
    float hin[4] = {0.f, 0.f, 0.f, 0.f};
    for (int c = 0; c < NCH; ++c) {
        size_t idx = ((((size_t)n * NCH + c) * 4 + q) * 256 + tid);
        float4 hl = *(float4*)&hloc[idx * 4];
        float S = Sbuf[(((size_t)n * NCH + c) * 4 + q) * 64 + ch];
        float4 hw = {hin[0], hin[1], hin[2], hin[3]};
        *(float4*)&hloc[idx * 4] = hw;
        hin[0] = hin[0] * __expf(A[0] * S) + hl.x;
        hin[1] = hin[1] * __expf(A[1] * S) + hl.y;
        hin[2] = hin[2] * __expf(A[2] * S) + hl.z;
        hin[3] = hin[3] * __expf(A[3] * S) + hl.w;
    }
}

// ============ kernel 5c: chunked scan pass 2 — full scan per chunk, y over delta ====
__global__ __launch_bounds__(256) void k_scan2(float* __restrict__ xz,
                                               const float* __restrict__ u,
                                               const float* __restrict__ xdbl,
                                               const float* __restrict__ alog,
                                               const float* __restrict__ hloc, int l) {
    const int n = blockIdx.x >> 5;
    const int c = (blockIdx.x >> 2) & 7;
    const int q = blockIdx.x & 3;
    const int tid = threadIdx.x;
    const int ch = tid >> 2, sg = tid & 3;
    const int d = q * 64 + ch;
    __shared__ float Bs[CH * DS];
    __shared__ float Cs[CH * DS];
    if (tid < 128) {
        int t = tid >> 2, sq = tid & 3;
        const float* row = xdbl + ((size_t)n * TT + c * CH + t) * XDBL;
        *(float4*)&Bs[t * DS + 4 * sq] = *(const float4*)&row[DTR + 4 * sq];
        *(float4*)&Cs[t * DS + 4 * sq] = *(const float4*)&row[DTR + DS + 4 * sq];
    }
    __syncthreads();
    float4 av = *(const float4*)&alog[((size_t)l * DI + d) * DS + sg * 4];
    float A[4] = {-__expf(av.x), -__expf(av.y), -__expf(av.z), -__expf(av.w)};
    float hst[4];
    {
        size_t idx = ((((size_t)n * NCH + c) * 4 + q) * 256 + tid);
        float4 hv = *(const float4*)&hloc[idx * 4];
        hst[0] = hv.x; hst[1] = hv.y; hst[2] = hv.z; hst[3] = hv.w;
    }

    float* dlt_p = xz + ((size_t)n * TT + c * CH) * (2 * DI) + d;   // delta in, y out
    const float* uv_p = u + ((size_t)n * TT + c * CH) * DI + d;
    float pD[16], pU[16];
#pragma unroll
    for (int j = 0; j < 16; ++j) {
        pD[j] = dlt_p[(size_t)j * (2 * DI)];
        pU[j] = uv_p[(size_t)j * DI];
    }
    for (int g = 0; g < 2; ++g) {
        float cD[16], cU[16];
#pragma unroll
        for (int j = 0; j < 16; ++j) { cD[j] = pD[j]; cU[j] = pU[j]; }
        if (g == 0) {
#pragma unroll
            for (int j = 0; j < 16; ++j) {
                pD[j] = dlt_p[(size_t)(16 + j) * (2 * DI)];
                pU[j] = uv_p[(size_t)(16 + j) * DI];
            }
        }
#pragma unroll
        for (int j = 0; j < 16; ++j) {
            const int t = g * 16 + j;
            float dlt = cD[j];
            float du = dlt * cU[j];
            const float* bt = Bs + t * DS + sg * 4;
            const float* ct = Cs + t * DS + sg * 4;
            float y = 0.f;
#pragma unroll
            for (int s = 0; s < 4; ++s) {
                float dA = __expf(dlt * A[s]);
                hst[s] = dA * hst[s] + du * bt[s];
                y += hst[s] * ct[s];
            }
            y += __shfl_xor(y, 1);
            y += __shfl_xor(y, 2);
            if (sg == 0)
                dlt_p[(size_t)t * (2 * DI)] = y;   // raw einsum result
        }
    }
}

// ============ kernel 6: gate + out_proj GEMM + residual + layernorm ============
// LDS strides 65/131 (odd): staging scatter conflict-free
__global__ __launch_bounds__(256) void k_outproj_ln(const float* __restrict__ xz,
                                                    const float* __restrict__ u,
                                                    const float* __restrict__ Dvec,
                                                    const float* __restrict__ opw,
                                                    float* __restrict__ h,
                                                    const float* __restrict__ nw,
                                                    const float* __restrict__ nb, int l) {
    __shared__ float As[64][65];
    __shared__ float Bs[64][131];
    const int m0 = blockIdx.x * 64;
    const int tid = threadIdx.x;
    const int ty = tid >> 4, tx = tid & 15;
    const float* wbase = opw + (size_t)l * DM * DI;
    float acc[4][8];
#pragma unroll
    for (int r = 0; r < 4; ++r)
#pragma unroll
        for (int c = 0; c < 8; ++c) acc[r][c] = 0.f;

    for (int k0 = 0; k0 < DI; k0 += 64) {
        const int kq = tid & 15, r0 = tid >> 4;
        float4 dv = *(const float4*)&Dvec[l * DI + k0 + 4 * kq];
#pragma unroll
        for (int i = 0; i < 4; ++i) {
            int row = r0 + 16 * i;
            size_t m = (size_t)(m0 + row);
            float4 yv = *(const float4*)&xz[m * (2 * DI) + k0 + 4 * kq];        // y_pre
            float4 uv = *(const float4*)&u[m * DI + k0 + 4 * kq];
            float4 zv = *(const float4*)&xz[m * (2 * DI) + DI + k0 + 4 * kq];   // z
            float4 v;
            v.x = (yv.x + uv.x * dv.x) * silu(zv.x);
            v.y = (yv.y + uv.y * dv.y) * silu(zv.y);
            v.z = (yv.z + uv.z * dv.z) * silu(zv.z);
            v.w = (yv.w + uv.w * dv.w) * silu(zv.w);
            As[4 * kq + 0][row] = v.x; As[4 * kq + 1][row] = v.y;
            As[4 * kq + 2][row] = v.z; As[4 * kq + 3][row] = v.w;
        }
#pragma unroll
        for (int i = 0; i < 8; ++i) {
            int col = r0 + 16 * i;
            float4 wv = *(const float4*)&wbase[(size_t)col * DI + k0 + 4 * kq];
            Bs[4 * kq + 0][col] = wv.x; Bs[4 * kq + 1][col] = wv.y;
            Bs[4 * kq + 2][col] = wv.z; Bs[4 * kq + 3][col] = wv.w;
        }
        __syncthreads();
#pragma unroll 8
        for (int k = 0; k < 64; ++k) {
            float4 a = *(float4*)&As[k][ty * 4];
            float4 b0 = *(float4*)&Bs[k][tx * 8];
            float4 b1 = *(float4*)&Bs[k][tx * 8 + 4];
            float av[4] = {a.x, a.y, a.z, a.w};
            float bv[8] = {b0.x, b0.y, b0.z, b0.w, b1.x, b1.y, b1.z, b1.w};
#pragma unroll
            for (int r = 0; r < 4; ++r)
#pragma unroll
                for (int c = 0; c < 8; ++c) acc[r][c] += av[r] * bv[c];
        }
        __syncthreads();
    }
#pragma unroll
    for (int r = 0; r < 4; ++r) {
        int row = m0 + ty * 4 + r;
        float4 h0 = *(float4*)&h[(size_t)row * DM + tx * 8];
        float4 h1 = *(float4*)&h[(size_t)row * DM + tx * 8 + 4];
        float v[8] = {acc[r][0] + h0.x, acc[r][1] + h0.y, acc[r][2] + h0.z, acc[r][3] + h0.w,
                      acc[r][4] + h1.x, acc[r][5] + h1.y, acc[r][6] + h1.z, acc[r][7] + h1.w};
        float s = 0.f, q = 0.f;
#pragma unroll
        for (int c = 0; c < 8; ++c) { s += v[c]; q += v[c] * v[c]; }
#pragma unroll
        for (int o = 1; o < 16; o <<= 1) { s += __shfl_xor(s, o); q += __shfl_xor(q, o); }
        float mu = s * (1.f / DM);
        float var = q * (1.f / DM) - mu * mu;
        float rs = rsqrtf(var + LN_EPS);
        float4 o0, o1;
        o0.x = (v[0] - mu) * rs * nw[l * DM + tx * 8 + 0] + nb[l * DM + tx * 8 + 0];
        o0.y = (v[1] - mu) * rs * nw[l * DM + tx * 8 + 1] + nb[l * DM + tx * 8 + 1];
        o0.z = (v[2] - mu) * rs * nw[l * DM + tx * 8 + 2] + nb[l * DM + tx * 8 + 2];
        o0.w = (v[3] - mu) * rs * nw[l * DM + tx * 8 + 3] + nb[l * DM + tx * 8 + 3];
        o1.x = (v[4] - mu) * rs * nw[l * DM + tx * 8 + 4] + nb[l * DM + tx * 8 + 4];
        o1.y = (v[5] - mu) * rs * nw[l * DM + tx * 8 + 5] + nb[l * DM + tx * 8 + 5];
        o1.z = (v[6] - mu) * rs * nw[l * DM + tx * 8 + 6] + nb[l * DM + tx * 8 + 6];
        o1.w = (v[7] - mu) * rs * nw[l * DM + tx * 8 + 7] + nb[l * DM + tx * 8 + 7];
        *(float4*)&h[(size_t)row * DM + tx * 8] = o0;
        *(float4*)&h[(size_t)row * DM + tx * 8 + 4] = o1;
    }
}

// ============ kernel 7: final layernorm + mean over T (parallel tokens) ============
__global__ __launch_bounds__(256) void k_final(const float* __restrict__ h,
                                               const float* __restrict__ ow,
                                               const float* __restrict__ ob,
                                               float* __restrict__ out) {
    const int n = blockIdx.x >> 2;
    const int quarter = blockIdx.x & 3;
    const int wave = threadIdx.x >> 6, lane = threadIdx.x & 63;
    const float w0 = ow[lane], w1 = ow[lane + 64];
    const float b0 = ob[lane], b1 = ob[lane + 64];
    float a0 = 0.f, a1 = 0.f;
    const int t0 = quarter * 64 + wave * 16;
#pragma unroll 4
    for (int i = 0; i < 16; ++i) {
        const float* row = h + ((size_t)n * TT + t0 + i) * DM;
        float v0 = row[lane], v1 = row[lane + 64];
        float s = v0 + v1, q = v0 * v0 + v1 * v1;
#pragma unroll
        for (int o = 1; o < 64; o <<= 1) { s += __shfl_xor(s, o); q += __shfl_xor(q, o); }
        float mu = s * (1.f / DM);
        float var = q * (1.f / DM) - mu * mu;
        float rs = rsqrtf(var + LN_EPS);
        a0 += (v0 - mu) * rs * w0 + b0;
        a1 += (v1 - mu) * rs * w1 + b1;
    }
    atomicAdd(&out[n * DM + lane], a0 * (1.f / TT));
    atomicAdd(&out[n * DM + lane + 64], a1 * (1.f / TT));
}

extern "C" void kernel_launch(void* const* d_in, const int* in_sizes, int n_in,
                              void* d_out, int out_size, void* d_ws, size_t ws_size,
                              hipStream_t stream) {
    const float* x     = (const float*)d_in[0];
    const float* inp_w = (const float*)d_in[1];
    const float* inp_b = (const float*)d_in[2];
    const float* ipw   = (const float*)d_in[3];
    const float* cw    = (const float*)d_in[4];
    const float* cb    = (const float*)d_in[5];
    const float* xpw   = (const float*)d_in[6];
    const float* dtw   = (const float*)d_in[7];
    const float* dtb   = (const float*)d_in[8];
    const float* alog  = (const float*)d_in[9];
    const float* Dv    = (const float*)d_in[10];
    const float* opw   = (const float*)d_in[11];
    const float* nw    = (const float*)d_in[12];
    const float* nb    = (const float*)d_in[13];
    const float* onw   = (const float*)d_in[14];
    const float* onb   = (const float*)d_in[15];

    float* base = (float*)d_ws;
    const size_t NT = (size_t)NSEQ * TT;
    float* h    = base;                 // NT*128
    float* xz   = h + NT * DM;          // NT*512  [xi -> delta -> y_pre | z]
    float* u    = xz + NT * 2 * DI;     // NT*256
    float* xdbl = u + NT * DI;          // NT*40
    float* hloc = xdbl + NT * XDBL;     // NSEQ*NCH*4*256*4
    float* Sbuf = hloc + (size_t)NSEQ * NCH * 4 * 256 * 4;

    k_input_proj<<<NT / 64, 256, 0, stream>>>(x, inp_w, inp_b, h);
    for (int l = 0; l < 2; ++l) {
        k_in_proj<<<(NT / 64) * 8, 256, 0, stream>>>(h, ipw, xz, l);
        k_conv<<<NT, 256, 0, stream>>>(xz, cw, cb, u, l);
        k_xd<<<NT / 64, 512, 0, stream>>>(u, xpw, dtw, dtb, xdbl, xz, l);
        k_scan1<<<NSEQ * 4 * NCH, 256, 0, stream>>>(xz, u, xdbl, alog, hloc, Sbuf, l);
        k_stitch<<<NSEQ * 4, 256, 0, stream>>>(hloc, Sbuf, alog, l);
        k_scan2<<<NSEQ * 4 * NCH, 256, 0, stream>>>(xz, u, xdbl, alog, hloc, l);
        k_outproj_ln<<<NT / 64, 256, 0, stream>>>(xz, u, Dv, opw, h, nw, nb, l);
    }
    hipMemsetAsync(d_out, 0, (size_t)out_size * sizeof(float), stream);
    k_final<<<NSEQ * 4, 256, 0, stream>>>(h, onw, onb, (float*)d_out);
}

// Round 15
// 423.523 us; speedup vs baseline: 1.1063x; 1.1063x over previous
//
#include <hip/hip_runtime.h>
#include <stdint.h>

#define NSEQ 64      // B*C
#define TT   256
#define FF   64
#define DM   128
#define DI   256
#define DS   16
#define DTR  8
#define XDBL 40      // DTR + 2*DS
#define CH   32      // scan chunk length
#define NCH  (TT / CH)
#define LN_EPS 1e-5f

__device__ __forceinline__ float silu(float v) { return v / (1.f + __expf(-v)); }

// ============ kernel 1: input projection GEMM ============
__global__ __launch_bounds__(256) void k_input_proj(const float* __restrict__ x,
                                                    const float* __restrict__ w,
                                                    const float* __restrict__ b,
                                                    float* __restrict__ h) {
    __shared__ float As[FF][68];    // As[f][local_t]
    __shared__ float Bs[FF][132];   // Bs[f][dm]
    const int m0 = blockIdx.x * 64;
    const int n = m0 >> 8, t0 = m0 & 255;
    const int tid = threadIdx.x;
    {
        const int tq = tid & 15, f0 = tid >> 4;
#pragma unroll
        for (int i = 0; i < 4; ++i) {
            int f = f0 + 16 * i;
            float4 v = *(const float4*)&x[((size_t)n * FF + f) * TT + t0 + 4 * tq];
            *(float4*)&As[f][4 * tq] = v;
        }
#pragma unroll
        for (int i = 0; i < 8; ++i) {
            int col = f0 + 16 * i;
            float4 v = *(const float4*)&w[(size_t)col * FF + 4 * tq];
            Bs[4 * tq + 0][col] = v.x; Bs[4 * tq + 1][col] = v.y;
            Bs[4 * tq + 2][col] = v.z; Bs[4 * tq + 3][col] = v.w;
        }
    }
    __syncthreads();
    const int ty = tid >> 4, tx = tid & 15;
    float acc[4][8];
#pragma unroll
    for (int r = 0; r < 4; ++r)
#pragma unroll
        for (int c = 0; c < 8; ++c) acc[r][c] = 0.f;
#pragma unroll 8
    for (int k = 0; k < FF; ++k) {
        float4 a = *(float4*)&As[k][ty * 4];
        float4 b0 = *(float4*)&Bs[k][tx * 8];
        float4 b1 = *(float4*)&Bs[k][tx * 8 + 4];
        float av[4] = {a.x, a.y, a.z, a.w};
        float bv[8] = {b0.x, b0.y, b0.z, b0.w, b1.x, b1.y, b1.z, b1.w};
#pragma unroll
        for (int r = 0; r < 4; ++r)
#pragma unroll
            for (int c = 0; c < 8; ++c) acc[r][c] += av[r] * bv[c];
    }
#pragma unroll
    for (int r = 0; r < 4; ++r) {
        int row = m0 + ty * 4 + r;
        float4 o0, o1;
        o0.x = acc[r][0] + b[tx * 8 + 0]; o0.y = acc[r][1] + b[tx * 8 + 1];
        o0.z = acc[r][2] + b[tx * 8 + 2]; o0.w = acc[r][3] + b[tx * 8 + 3];
        o1.x = acc[r][4] + b[tx * 8 + 4]; o1.y = acc[r][5] + b[tx * 8 + 5];
        o1.z = acc[r][6] + b[tx * 8 + 6]; o1.w = acc[r][7] + b[tx * 8 + 7];
        *(float4*)&h[(size_t)row * DM + tx * 8] = o0;
        *(float4*)&h[(size_t)row * DM + tx * 8 + 4] = o1;
    }
}

// ============ kernel 2: in_proj GEMM, 128x128 tile, BK=32, 8x8/thread ============
// M=16384, N=512, K=128. grid = 128*4 = 512 blocks. 16:1 FMA:LDS-read ratio.
__global__ __launch_bounds__(256) void k_in_proj(const float* __restrict__ h,
                                                 const float* __restrict__ ipw,
                                                 float* __restrict__ xz, int l) {
    __shared__ float As[32][132];   // As[k][m]
    __shared__ float Bs[32][132];   // Bs[k][n]
    const int m0 = (blockIdx.x >> 2) * 128;
    const int n0 = (blockIdx.x & 3) * 128;
    const int tid = threadIdx.x;
    const int ty = tid >> 4, tx = tid & 15;   // 16x16 thread grid, 8x8 microtile
    const float* wbase = ipw + (size_t)l * 2 * DI * DM;
    float acc[8][8];
#pragma unroll
    for (int r = 0; r < 8; ++r)
#pragma unroll
        for (int c = 0; c < 8; ++c) acc[r][c] = 0.f;

    const int kq = tid & 7, r0 = tid >> 3;    // staging: 8 kq x 32 rows
    for (int k0 = 0; k0 < DM; k0 += 32) {
#pragma unroll
        for (int i = 0; i < 4; ++i) {
            int row = r0 + 32 * i;
            float4 v = *(const float4*)&h[(size_t)(m0 + row) * DM + k0 + 4 * kq];
            As[4 * kq + 0][row] = v.x; As[4 * kq + 1][row] = v.y;
            As[4 * kq + 2][row] = v.z; As[4 * kq + 3][row] = v.w;
            float4 wv = *(const float4*)&wbase[(size_t)(n0 + row) * DM + k0 + 4 * kq];
            Bs[4 * kq + 0][row] = wv.x; Bs[4 * kq + 1][row] = wv.y;
            Bs[4 * kq + 2][row] = wv.z; Bs[4 * kq + 3][row] = wv.w;
        }
        __syncthreads();
#pragma unroll 4
        for (int k = 0; k < 32; ++k) {
            float4 a0 = *(float4*)&As[k][ty * 8];
            float4 a1 = *(float4*)&As[k][ty * 8 + 4];
            float4 b0 = *(float4*)&Bs[k][tx * 8];
            float4 b1 = *(float4*)&Bs[k][tx * 8 + 4];
            float av[8] = {a0.x, a0.y, a0.z, a0.w, a1.x, a1.y, a1.z, a1.w};
            float bv[8] = {b0.x, b0.y, b0.z, b0.w, b1.x, b1.y, b1.z, b1.w};
#pragma unroll
            for (int r = 0; r < 8; ++r)
#pragma unroll
                for (int c = 0; c < 8; ++c) acc[r][c] += av[r] * bv[c];
        }
        __syncthreads();
    }
#pragma unroll
    for (int r = 0; r < 8; ++r) {
        int row = m0 + ty * 8 + r;
        float4 o0 = {acc[r][0], acc[r][1], acc[r][2], acc[r][3]};
        float4 o1 = {acc[r][4], acc[r][5], acc[r][6], acc[r][7]};
        *(float4*)&xz[(size_t)row * (2 * DI) + n0 + tx * 8] = o0;
        *(float4*)&xz[(size_t)row * (2 * DI) + n0 + tx * 8 + 4] = o1;
    }
}

// ============ kernel 3: causal depthwise conv + silu -> u ============
__global__ __launch_bounds__(256) void k_conv(const float* __restrict__ xz,
                                              const float* __restrict__ cw,
                                              const float* __restrict__ cb,
                                              float* __restrict__ u, int l) {
    int idx = blockIdx.x * 256 + threadIdx.x;
    int d = idx & (DI - 1);
    int nt = idx >> 8;
    int t = nt & 255;
    const float* wr = cw + ((size_t)l * DI + d) * 4;
    float acc = cb[l * DI + d];
#pragma unroll
    for (int j = 0; j < 4; ++j) {
        int back = 3 - j;
        if (t - back >= 0)
            acc += xz[(size_t)(nt - back) * (2 * DI) + d] * wr[j];
    }
    u[(size_t)nt * DI + d] = silu(acc);
}

// ============ kernel 4: x_dbl GEMM, K-split x2, full-K LDS stage + fused delta ======
__global__ __launch_bounds__(512) void k_xd(const float* __restrict__ u,
                                            const float* __restrict__ xpw,
                                            const float* __restrict__ dtw,
                                            const float* __restrict__ dtb,
                                            float* __restrict__ xdbl,
                                            float* __restrict__ xz, int l) {
    __shared__ float As[64][260];
    __shared__ float Bs[XDBL][260];
    __shared__ float xdS[64][41];
    const int m0 = blockIdx.x * 64;
    const int tid = threadIdx.x;
    const int hk = tid >> 8;         // K-half
    const int t2 = tid & 255;
    const int ty = t2 >> 3;
    const int tx = t2 & 7;
    for (int i = tid; i < 64 * 64; i += 512) {
        int r = i >> 6, c = (i & 63) * 4;
        *(float4*)&As[r][c] = *(const float4*)&u[(size_t)(m0 + r) * DI + c];
    }
    const float* wbase = xpw + (size_t)l * XDBL * DI;
    for (int i = tid; i < XDBL * 64; i += 512) {
        int r = i >> 6, c = (i & 63) * 4;
        *(float4*)&Bs[r][c] = *(const float4*)&wbase[(size_t)r * DI + c];
    }
    __syncthreads();
    float acc[2][5];
#pragma unroll
    for (int r = 0; r < 2; ++r)
#pragma unroll
        for (int c = 0; c < 5; ++c) acc[r][c] = 0.f;
    const int kbase = hk * 128;
#pragma unroll 4
    for (int kk = 0; kk < 128; kk += 4) {
        const int k = kbase + kk;
        float4 a0 = *(float4*)&As[2 * ty][k];
        float4 a1 = *(float4*)&As[2 * ty + 1][k];
        float4 b[5];
#pragma unroll
        for (int c = 0; c < 5; ++c) b[c] = *(float4*)&Bs[5 * tx + c][k];
#pragma unroll
        for (int c = 0; c < 5; ++c) {
            acc[0][c] += a0.x * b[c].x + a0.y * b[c].y + a0.z * b[c].z + a0.w * b[c].w;
            acc[1][c] += a1.x * b[c].x + a1.y * b[c].y + a1.z * b[c].z + a1.w * b[c].w;
        }
    }
    if (hk == 0) {
#pragma unroll
        for (int r = 0; r < 2; ++r)
#pragma unroll
            for (int c = 0; c < 5; ++c) xdS[2 * ty + r][5 * tx + c] = acc[r][c];
    }
    __syncthreads();
    if (hk == 1) {
#pragma unroll
        for (int r = 0; r < 2; ++r)
#pragma unroll
            for (int c = 0; c < 5; ++c) {
                int m = 2 * ty + r, col = 5 * tx + c;
                float v = xdS[m][col] + acc[r][c];
                xdS[m][col] = v;
                xdbl[(size_t)(m0 + m) * XDBL + col] = v;
            }
    }
    __syncthreads();
    {
        const int ch = tid & 255;
        const int tk0 = hk * 32;
        float4 dw0 = *(const float4*)&dtw[((size_t)l * DI + ch) * DTR];
        float4 dw1 = *(const float4*)&dtw[((size_t)l * DI + ch) * DTR + 4];
        const float bias = dtb[l * DI + ch];
#pragma unroll 8
        for (int tk = tk0; tk < tk0 + 32; ++tk) {
            const float* xr = xdS[tk];
            float a = bias + xr[0] * dw0.x + xr[1] * dw0.y + xr[2] * dw0.z + xr[3] * dw0.w
                           + xr[4] * dw1.x + xr[5] * dw1.y + xr[6] * dw1.z + xr[7] * dw1.w;
            float sp = (a > 20.f) ? a : log1pf(__expf(a));
            xz[(size_t)(m0 + tk) * (2 * DI) + ch] = sp;
        }
    }
}

// ============ kernel 5a: chunked scan pass 1 — local states + delta sums ============
__global__ __launch_bounds__(256) void k_scan1(const float* __restrict__ xz,
                                               const float* __restrict__ u,
                                               const float* __restrict__ xdbl,
                                               const float* __restrict__ alog,
                                               float* __restrict__ hloc,
                                               float* __restrict__ Sbuf, int l) {
    const int n = blockIdx.x >> 5;
    const int c = (blockIdx.x >> 2) & 7;
    const int q = blockIdx.x & 3;
    const int tid = threadIdx.x;
    const int ch = tid >> 2, sg = tid & 3;
    const int d = q * 64 + ch;
    __shared__ float Bs[CH * DS];
    if (tid < 128) {
        int t = tid >> 2, sq = tid & 3;
        const float* row = xdbl + ((size_t)n * TT + c * CH + t) * XDBL;
        *(float4*)&Bs[t * DS + 4 * sq] = *(const float4*)&row[DTR + 4 * sq];
    }
    __syncthreads();
    float4 av = *(const float4*)&alog[((size_t)l * DI + d) * DS + sg * 4];
    float A[4] = {-__expf(av.x), -__expf(av.y), -__expf(av.z), -__expf(av.w)};
    float hst[4] = {0.f, 0.f, 0.f, 0.f};
    float S = 0.f;

    const float* dlt_p = xz + ((size_t)n * TT + c * CH) * (2 * DI) + d;
    const float* uv_p  = u + ((size_t)n * TT + c * CH) * DI + d;
    float pD[16], pU[16];
#pragma unroll
    for (int j = 0; j < 16; ++j) {
        pD[j] = dlt_p[(size_t)j * (2 * DI)];
        pU[j] = uv_p[(size_t)j * DI];
    }
    for (int g = 0; g < 2; ++g) {
        float cD[16], cU[16];
#pragma unroll
        for (int j = 0; j < 16; ++j) { cD[j] = pD[j]; cU[j] = pU[j]; }
        if (g == 0) {
#pragma unroll
            for (int j = 0; j < 16; ++j) {
                pD[j] = dlt_p[(size_t)(16 + j) * (2 * DI)];
                pU[j] = uv_p[(size_t)(16 + j) * DI];
            }
        }
#pragma unroll
        for (int j = 0; j < 16; ++j) {
            const int t = g * 16 + j;
            float dlt = cD[j];
            float du = dlt * cU[j];
            const float* bt = Bs + t * DS + sg * 4;
            S += dlt;
#pragma unroll
            for (int s = 0; s < 4; ++s) {
                float dA = __expf(dlt * A[s]);
                hst[s] = dA * hst[s] + du * bt[s];
            }
        }
    }
    size_t idx = ((((size_t)n * NCH + c) * 4 + q) * 256 + tid);
    float4 hv = {hst[0], hst[1], hst[2], hst[3]};
    *(float4*)&hloc[idx * 4] = hv;
    if (sg == 0) Sbuf[(((size_t)n * NCH + c) * 4 + q) * 64 + ch] = S;
}

// ============ kernel 5b: stitch — serial prefix over chunks, hloc := h_in ============
__global__ __launch_bounds__(256) void k_stitch(float* __restrict__ hloc,
                                                const float* __restrict__ Sbuf,
                                                const float* __restrict__ alog, int l) {
    const int n = blockIdx.x >> 2;
    const int q = blockIdx.x & 3;
    const int tid = threadIdx.x;
    const int ch = tid >> 2, sg = tid & 3;
    const int d = q * 64 + ch;
    float4 av = *(const float4*)&alog[((size_t)l * DI + d) * DS + sg * 4];
    float A[4] = {-__expf(av.x), -__expf(av.y), -__expf(av.z), -__expf(av.w)};
    float hin[4] = {0.f, 0.f, 0.f, 0.f};
    for (int c = 0; c < NCH; ++c) {
        size_t idx = ((((size_t)n * NCH + c) * 4 + q) * 256 + tid);
        float4 hl = *(float4*)&hloc[idx * 4];
        float S = Sbuf[(((size_t)n * NCH + c) * 4 + q) * 64 + ch];
        float4 hw = {hin[0], hin[1], hin[2], hin[3]};
        *(float4*)&hloc[idx * 4] = hw;
        hin[0] = hin[0] * __expf(A[0] * S) + hl.x;
        hin[1] = hin[1] * __expf(A[1] * S) + hl.y;
        hin[2] = hin[2] * __expf(A[2] * S) + hl.z;
        hin[3] = hin[3] * __expf(A[3] * S) + hl.w;
    }
}

// ============ kernel 5c: chunked scan pass 2 — full scan per chunk, y over delta ====
__global__ __launch_bounds__(256) void k_scan2(float* __restrict__ xz,
                                               const float* __restrict__ u,
                                               const float* __restrict__ xdbl,
                                               const float* __restrict__ alog,
                                               const float* __restrict__ hloc, int l) {
    const int n = blockIdx.x >> 5;
    const int c = (blockIdx.x >> 2) & 7;
    const int q = blockIdx.x & 3;
    const int tid = threadIdx.x;
    const int ch = tid >> 2, sg = tid & 3;
    const int d = q * 64 + ch;
    __shared__ float Bs[CH * DS];
    __shared__ float Cs[CH * DS];
    if (tid < 128) {
        int t = tid >> 2, sq = tid & 3;
        const float* row = xdbl + ((size_t)n * TT + c * CH + t) * XDBL;
        *(float4*)&Bs[t * DS + 4 * sq] = *(const float4*)&row[DTR + 4 * sq];
        *(float4*)&Cs[t * DS + 4 * sq] = *(const float4*)&row[DTR + DS + 4 * sq];
    }
    __syncthreads();
    float4 av = *(const float4*)&alog[((size_t)l * DI + d) * DS + sg * 4];
    float A[4] = {-__expf(av.x), -__expf(av.y), -__expf(av.z), -__expf(av.w)};
    float hst[4];
    {
        size_t idx = ((((size_t)n * NCH + c) * 4 + q) * 256 + tid);
        float4 hv = *(const float4*)&hloc[idx * 4];
        hst[0] = hv.x; hst[1] = hv.y; hst[2] = hv.z; hst[3] = hv.w;
    }

    float* dlt_p = xz + ((size_t)n * TT + c * CH) * (2 * DI) + d;   // delta in, y out
    const float* uv_p = u + ((size_t)n * TT + c * CH) * DI + d;
    float pD[16], pU[16];
#pragma unroll
    for (int j = 0; j < 16; ++j) {
        pD[j] = dlt_p[(size_t)j * (2 * DI)];
        pU[j] = uv_p[(size_t)j * DI];
    }
    for (int g = 0; g < 2; ++g) {
        float cD[16], cU[16];
#pragma unroll
        for (int j = 0; j < 16; ++j) { cD[j] = pD[j]; cU[j] = pU[j]; }
        if (g == 0) {
#pragma unroll
            for (int j = 0; j < 16; ++j) {
                pD[j] = dlt_p[(size_t)(16 + j) * (2 * DI)];
                pU[j] = uv_p[(size_t)(16 + j) * DI];
            }
        }
#pragma unroll
        for (int j = 0; j < 16; ++j) {
            const int t = g * 16 + j;
            float dlt = cD[j];
            float du = dlt * cU[j];
            const float* bt = Bs + t * DS + sg * 4;
            const float* ct = Cs + t * DS + sg * 4;
            float y = 0.f;
#pragma unroll
            for (int s = 0; s < 4; ++s) {
                float dA = __expf(dlt * A[s]);
                hst[s] = dA * hst[s] + du * bt[s];
                y += hst[s] * ct[s];
            }
            y += __shfl_xor(y, 1);
            y += __shfl_xor(y, 2);
            if (sg == 0)
                dlt_p[(size_t)t * (2 * DI)] = y;   // raw einsum result
        }
    }
}

// ============ kernel 6: gate + out_proj GEMM + residual + layernorm ============
__global__ __launch_bounds__(256) void k_outproj_ln(const float* __restrict__ xz,
                                                    const float* __restrict__ u,
                                                    const float* __restrict__ Dvec,
                                                    const float* __restrict__ opw,
                                                    float* __restrict__ h,
                                                    const float* __restrict__ nw,
                                                    const float* __restrict__ nb, int l) {
    __shared__ float As[64][68];
    __shared__ float Bs[64][132];
    const int m0 = blockIdx.x * 64;
    const int tid = threadIdx.x;
    const int ty = tid >> 4, tx = tid & 15;
    const float* wbase = opw + (size_t)l * DM * DI;
    float acc[4][8];
#pragma unroll
    for (int r = 0; r < 4; ++r)
#pragma unroll
        for (int c = 0; c < 8; ++c) acc[r][c] = 0.f;

    for (int k0 = 0; k0 < DI; k0 += 64) {
        const int kq = tid & 15, r0 = tid >> 4;
        float4 dv = *(const float4*)&Dvec[l * DI + k0 + 4 * kq];
#pragma unroll
        for (int i = 0; i < 4; ++i) {
            int row = r0 + 16 * i;
            size_t m = (size_t)(m0 + row);
            float4 yv = *(const float4*)&xz[m * (2 * DI) + k0 + 4 * kq];        // y_pre
            float4 uv = *(const float4*)&u[m * DI + k0 + 4 * kq];
            float4 zv = *(const float4*)&xz[m * (2 * DI) + DI + k0 + 4 * kq];   // z
            float4 v;
            v.x = (yv.x + uv.x * dv.x) * silu(zv.x);
            v.y = (yv.y + uv.y * dv.y) * silu(zv.y);
            v.z = (yv.z + uv.z * dv.z) * silu(zv.z);
            v.w = (yv.w + uv.w * dv.w) * silu(zv.w);
            As[4 * kq + 0][row] = v.x; As[4 * kq + 1][row] = v.y;
            As[4 * kq + 2][row] = v.z; As[4 * kq + 3][row] = v.w;
        }
#pragma unroll
        for (int i = 0; i < 8; ++i) {
            int col = r0 + 16 * i;
            float4 wv = *(const float4*)&wbase[(size_t)col * DI + k0 + 4 * kq];
            Bs[4 * kq + 0][col] = wv.x; Bs[4 * kq + 1][col] = wv.y;
            Bs[4 * kq + 2][col] = wv.z; Bs[4 * kq + 3][col] = wv.w;
        }
        __syncthreads();
#pragma unroll 8
        for (int k = 0; k < 64; ++k) {
            float4 a = *(float4*)&As[k][ty * 4];
            float4 b0 = *(float4*)&Bs[k][tx * 8];
            float4 b1 = *(float4*)&Bs[k][tx * 8 + 4];
            float av[4] = {a.x, a.y, a.z, a.w};
            float bv[8] = {b0.x, b0.y, b0.z, b0.w, b1.x, b1.y, b1.z, b1.w};
#pragma unroll
            for (int r = 0; r < 4; ++r)
#pragma unroll
                for (int c = 0; c < 8; ++c) acc[r][c] += av[r] * bv[c];
        }
        __syncthreads();
    }
#pragma unroll
    for (int r = 0; r < 4; ++r) {
        int row = m0 + ty * 4 + r;
        float4 h0 = *(float4*)&h[(size_t)row * DM + tx * 8];
        float4 h1 = *(float4*)&h[(size_t)row * DM + tx * 8 + 4];
        float v[8] = {acc[r][0] + h0.x, acc[r][1] + h0.y, acc[r][2] + h0.z, acc[r][3] + h0.w,
                      acc[r][4] + h1.x, acc[r][5] + h1.y, acc[r][6] + h1.z, acc[r][7] + h1.w};
        float s = 0.f, q = 0.f;
#pragma unroll
        for (int c = 0; c < 8; ++c) { s += v[c]; q += v[c] * v[c]; }
#pragma unroll
        for (int o = 1; o < 16; o <<= 1) { s += __shfl_xor(s, o); q += __shfl_xor(q, o); }
        float mu = s * (1.f / DM);
        float var = q * (1.f / DM) - mu * mu;
        float rs = rsqrtf(var + LN_EPS);
        float4 o0, o1;
        o0.x = (v[0] - mu) * rs * nw[l * DM + tx * 8 + 0] + nb[l * DM + tx * 8 + 0];
        o0.y = (v[1] - mu) * rs * nw[l * DM + tx * 8 + 1] + nb[l * DM + tx * 8 + 1];
        o0.z = (v[2] - mu) * rs * nw[l * DM + tx * 8 + 2] + nb[l * DM + tx * 8 + 2];
        o0.w = (v[3] - mu) * rs * nw[l * DM + tx * 8 + 3] + nb[l * DM + tx * 8 + 3];
        o1.x = (v[4] - mu) * rs * nw[l * DM + tx * 8 + 4] + nb[l * DM + tx * 8 + 4];
        o1.y = (v[5] - mu) * rs * nw[l * DM + tx * 8 + 5] + nb[l * DM + tx * 8 + 5];
        o1.z = (v[6] - mu) * rs * nw[l * DM + tx * 8 + 6] + nb[l * DM + tx * 8 + 6];
        o1.w = (v[7] - mu) * rs * nw[l * DM + tx * 8 + 7] + nb[l * DM + tx * 8 + 7];
        *(float4*)&h[(size_t)row * DM + tx * 8] = o0;
        *(float4*)&h[(size_t)row * DM + tx * 8 + 4] = o1;
    }
}

// ============ kernel 7: final layernorm + mean over T (parallel tokens) ============
__global__ __launch_bounds__(256) void k_final(const float* __restrict__ h,
                                               const float* __restrict__ ow,
                                               const float* __restrict__ ob,
                                               float* __restrict__ out) {
    const int n = blockIdx.x >> 2;
    const int quarter = blockIdx.x & 3;
    const int wave = threadIdx.x >> 6, lane = threadIdx.x & 63;
    const float w0 = ow[lane], w1 = ow[lane + 64];
    const float b0 = ob[lane], b1 = ob[lane + 64];
    float a0 = 0.f, a1 = 0.f;
    const int t0 = quarter * 64 + wave * 16;
#pragma unroll 4
    for (int i = 0; i < 16; ++i) {
        const float* row = h + ((size_t)n * TT + t0 + i) * DM;
        float v0 = row[lane], v1 = row[lane + 64];
        float s = v0 + v1, q = v0 * v0 + v1 * v1;
#pragma unroll
        for (int o = 1; o < 64; o <<= 1) { s += __shfl_xor(s, o); q += __shfl_xor(q, o); }
        float mu = s * (1.f / DM);
        float var = q * (1.f / DM) - mu * mu;
        float rs = rsqrtf(var + LN_EPS);
        a0 += (v0 - mu) * rs * w0 + b0;
        a1 += (v1 - mu) * rs * w1 + b1;
    }
    atomicAdd(&out[n * DM + lane], a0 * (1.f / TT));
    atomicAdd(&out[n * DM + lane + 64], a1 * (1.f / TT));
}

extern "C" void kernel_launch(void* const* d_in, const int* in_sizes, int n_in,
                              void* d_out, int out_size, void* d_ws, size_t ws_size,
                              hipStream_t stream) {
    const float* x     = (const float*)d_in[0];
    const float* inp_w = (const float*)d_in[1];
    const float* inp_b = (const float*)d_in[2];
    const float* ipw   = (const float*)d_in[3];
    const float* cw    = (const float*)d_in[4];
    const float* cb    = (const float*)d_in[5];
    const float* xpw   = (const float*)d_in[6];
    const float* dtw   = (const float*)d_in[7];
    const float* dtb   = (const float*)d_in[8];
    const float* alog  = (const float*)d_in[9];
    const float* Dv    = (const float*)d_in[10];
    const float* opw   = (const float*)d_in[11];
    const float* nw    = (const float*)d_in[12];
    const float* nb    = (const float*)d_in[13];
    const float* onw   = (const float*)d_in[14];
    const float* onb   = (const float*)d_in[15];

    float* base = (float*)d_ws;
    const size_t NT = (size_t)NSEQ * TT;
    float* h    = base;                 // NT*128
    float* xz   = h + NT * DM;          // NT*512  [xi -> delta -> y_pre | z]
    float* u    = xz + NT * 2 * DI;     // NT*256
    float* xdbl = u + NT * DI;          // NT*40
    float* hloc = xdbl + NT * XDBL;     // NSEQ*NCH*4*256*4
    float* Sbuf = hloc + (size_t)NSEQ * NCH * 4 * 256 * 4;

    k_input_proj<<<NT / 64, 256, 0, stream>>>(x, inp_w, inp_b, h);
    for (int l = 0; l < 2; ++l) {
        k_in_proj<<<(NT / 128) * 4, 256, 0, stream>>>(h, ipw, xz, l);
        k_conv<<<NT, 256, 0, stream>>>(xz, cw, cb, u, l);
        k_xd<<<NT / 64, 512, 0, stream>>>(u, xpw, dtw, dtb, xdbl, xz, l);
        k_scan1<<<NSEQ * 4 * NCH, 256, 0, stream>>>(xz, u, xdbl, alog, hloc, Sbuf, l);
        k_stitch<<<NSEQ * 4, 256, 0, stream>>>(hloc, Sbuf, alog, l);
        k_scan2<<<NSEQ * 4 * NCH, 256, 0, stream>>>(xz, u, xdbl, alog, hloc, l);
        k_outproj_ln<<<NT / 64, 256, 0, stream>>>(xz, u, Dv, opw, h, nw, nb, l);
    }
    hipMemsetAsync(d_out, 0, (size_t)out_size * sizeof(float), stream);
    k_final<<<NSEQ * 4, 256, 0, stream>>>(h, onw, onb, (float*)d_out);
}

// Round 16
// 400.431 us; speedup vs baseline: 1.1701x; 1.0577x over previous
//
#include <hip/hip_runtime.h>
#include <stdint.h>

#define NSEQ 64      // B*C
#define TT   256
#define FF   64
#define DM   128
#define DI   256
#define DS   16
#define DTR  8
#define XDBL 40      // DTR + 2*DS
#define CH   32      // scan chunk length
#define NCH  (TT / CH)
#define LN_EPS 1e-5f

__device__ __forceinline__ float silu(float v) { return v / (1.f + __expf(-v)); }

// ============ kernel 1: input projection GEMM ============
__global__ __launch_bounds__(256) void k_input_proj(const float* __restrict__ x,
                                                    const float* __restrict__ w,
                                                    const float* __restrict__ b,
                                                    float* __restrict__ h) {
    __shared__ float As[FF][68];    // As[f][local_t]
    __shared__ float Bs[FF][132];   // Bs[f][dm]
    const int m0 = blockIdx.x * 64;
    const int n = m0 >> 8, t0 = m0 & 255;
    const int tid = threadIdx.x;
    {
        const int tq = tid & 15, f0 = tid >> 4;
#pragma unroll
        for (int i = 0; i < 4; ++i) {
            int f = f0 + 16 * i;
            float4 v = *(const float4*)&x[((size_t)n * FF + f) * TT + t0 + 4 * tq];
            *(float4*)&As[f][4 * tq] = v;
        }
#pragma unroll
        for (int i = 0; i < 8; ++i) {
            int col = f0 + 16 * i;
            float4 v = *(const float4*)&w[(size_t)col * FF + 4 * tq];
            Bs[4 * tq + 0][col] = v.x; Bs[4 * tq + 1][col] = v.y;
            Bs[4 * tq + 2][col] = v.z; Bs[4 * tq + 3][col] = v.w;
        }
    }
    __syncthreads();
    const int ty = tid >> 4, tx = tid & 15;
    float acc[4][8];
#pragma unroll
    for (int r = 0; r < 4; ++r)
#pragma unroll
        for (int c = 0; c < 8; ++c) acc[r][c] = 0.f;
#pragma unroll 8
    for (int k = 0; k < FF; ++k) {
        float4 a = *(float4*)&As[k][ty * 4];
        float4 b0 = *(float4*)&Bs[k][tx * 8];
        float4 b1 = *(float4*)&Bs[k][tx * 8 + 4];
        float av[4] = {a.x, a.y, a.z, a.w};
        float bv[8] = {b0.x, b0.y, b0.z, b0.w, b1.x, b1.y, b1.z, b1.w};
#pragma unroll
        for (int r = 0; r < 4; ++r)
#pragma unroll
            for (int c = 0; c < 8; ++c) acc[r][c] += av[r] * bv[c];
    }
#pragma unroll
    for (int r = 0; r < 4; ++r) {
        int row = m0 + ty * 4 + r;
        float4 o0, o1;
        o0.x = acc[r][0] + b[tx * 8 + 0]; o0.y = acc[r][1] + b[tx * 8 + 1];
        o0.z = acc[r][2] + b[tx * 8 + 2]; o0.w = acc[r][3] + b[tx * 8 + 3];
        o1.x = acc[r][4] + b[tx * 8 + 4]; o1.y = acc[r][5] + b[tx * 8 + 5];
        o1.z = acc[r][6] + b[tx * 8 + 6]; o1.w = acc[r][7] + b[tx * 8 + 7];
        *(float4*)&h[(size_t)row * DM + tx * 8] = o0;
        *(float4*)&h[(size_t)row * DM + tx * 8 + 4] = o1;
    }
}

// ============ kernel 2: in_proj GEMM, 128x128 tile, BK=32, 8x8/thread ============
__global__ __launch_bounds__(256) void k_in_proj(const float* __restrict__ h,
                                                 const float* __restrict__ ipw,
                                                 float* __restrict__ xz, int l) {
    __shared__ float As[32][132];   // As[k][m]
    __shared__ float Bs[32][132];   // Bs[k][n]
    const int m0 = (blockIdx.x >> 2) * 128;
    const int n0 = (blockIdx.x & 3) * 128;
    const int tid = threadIdx.x;
    const int ty = tid >> 4, tx = tid & 15;
    const float* wbase = ipw + (size_t)l * 2 * DI * DM;
    float acc[8][8];
#pragma unroll
    for (int r = 0; r < 8; ++r)
#pragma unroll
        for (int c = 0; c < 8; ++c) acc[r][c] = 0.f;

    const int kq = tid & 7, r0 = tid >> 3;
    for (int k0 = 0; k0 < DM; k0 += 32) {
#pragma unroll
        for (int i = 0; i < 4; ++i) {
            int row = r0 + 32 * i;
            float4 v = *(const float4*)&h[(size_t)(m0 + row) * DM + k0 + 4 * kq];
            As[4 * kq + 0][row] = v.x; As[4 * kq + 1][row] = v.y;
            As[4 * kq + 2][row] = v.z; As[4 * kq + 3][row] = v.w;
            float4 wv = *(const float4*)&wbase[(size_t)(n0 + row) * DM + k0 + 4 * kq];
            Bs[4 * kq + 0][row] = wv.x; Bs[4 * kq + 1][row] = wv.y;
            Bs[4 * kq + 2][row] = wv.z; Bs[4 * kq + 3][row] = wv.w;
        }
        __syncthreads();
#pragma unroll 4
        for (int k = 0; k < 32; ++k) {
            float4 a0 = *(float4*)&As[k][ty * 8];
            float4 a1 = *(float4*)&As[k][ty * 8 + 4];
            float4 b0 = *(float4*)&Bs[k][tx * 8];
            float4 b1 = *(float4*)&Bs[k][tx * 8 + 4];
            float av[8] = {a0.x, a0.y, a0.z, a0.w, a1.x, a1.y, a1.z, a1.w};
            float bv[8] = {b0.x, b0.y, b0.z, b0.w, b1.x, b1.y, b1.z, b1.w};
#pragma unroll
            for (int r = 0; r < 8; ++r)
#pragma unroll
                for (int c = 0; c < 8; ++c) acc[r][c] += av[r] * bv[c];
        }
        __syncthreads();
    }
#pragma unroll
    for (int r = 0; r < 8; ++r) {
        int row = m0 + ty * 8 + r;
        float4 o0 = {acc[r][0], acc[r][1], acc[r][2], acc[r][3]};
        float4 o1 = {acc[r][4], acc[r][5], acc[r][6], acc[r][7]};
        *(float4*)&xz[(size_t)row * (2 * DI) + n0 + tx * 8] = o0;
        *(float4*)&xz[(size_t)row * (2 * DI) + n0 + tx * 8 + 4] = o1;
    }
}

// ============ kernel 3: fused conv+silu + x_dbl GEMM + delta ============
// grid = NT/64, 512 threads. Staging computes u = silu(conv(xi)) from xz (xi slot,
// never overwritten), writes u to LDS (GEMM A) and global. K-split x2 GEMM.
// Epilogue: delta -> dlt buffer (separate; avoids cross-block xi hazard).
__global__ __launch_bounds__(512) void k_xd(const float* __restrict__ xz,
                                            float* __restrict__ u,
                                            const float* __restrict__ cw,
                                            const float* __restrict__ cb,
                                            const float* __restrict__ xpw,
                                            const float* __restrict__ dtw,
                                            const float* __restrict__ dtb,
                                            float* __restrict__ xdbl,
                                            float* __restrict__ dlt, int l) {
    __shared__ float As[64][260];
    __shared__ float Bs[XDBL][260];
    __shared__ float xdS[64][41];
    const int m0 = blockIdx.x * 64;
    const int t0 = m0 & 255;
    const int tid = threadIdx.x;
    // --- staging: conv+silu -> As + u global ---
    {
        const int colf = (tid & 63) * 4;      // fixed channel col per thread
        const int rbase = tid >> 6;           // rows rbase + 8j
        const float* wp = cw + ((size_t)l * DI + colf) * 4;
        float4 w0 = *(const float4*)&wp[0];   // taps of ch colf   (j=0..3)
        float4 w1 = *(const float4*)&wp[4];
        float4 w2 = *(const float4*)&wp[8];
        float4 w3 = *(const float4*)&wp[12];
        float4 cbv = *(const float4*)&cb[l * DI + colf];
#pragma unroll
        for (int j = 0; j < 8; ++j) {
            int r = rbase + 8 * j;
            int t = t0 + r;
            const float* xp = xz + (size_t)(m0 + r) * 512 + colf;
            float4 z4 = {0.f, 0.f, 0.f, 0.f};
            float4 xm3 = (t >= 3) ? *(const float4*)(xp - 3 * 512) : z4;
            float4 xm2 = (t >= 2) ? *(const float4*)(xp - 2 * 512) : z4;
            float4 xm1 = (t >= 1) ? *(const float4*)(xp - 512) : z4;
            float4 x00 = *(const float4*)xp;
            float4 uv;
            uv.x = silu(cbv.x + w0.x * xm3.x + w0.y * xm2.x + w0.z * xm1.x + w0.w * x00.x);
            uv.y = silu(cbv.y + w1.x * xm3.y + w1.y * xm2.y + w1.z * xm1.y + w1.w * x00.y);
            uv.z = silu(cbv.z + w2.x * xm3.z + w2.y * xm2.z + w2.z * xm1.z + w2.w * x00.z);
            uv.w = silu(cbv.w + w3.x * xm3.w + w3.y * xm2.w + w3.z * xm1.w + w3.w * x00.w);
            *(float4*)&As[r][colf] = uv;
            *(float4*)&u[(size_t)(m0 + r) * DI + colf] = uv;
        }
    }
    const float* wbase = xpw + (size_t)l * XDBL * DI;
    for (int i = tid; i < XDBL * 64; i += 512) {
        int r = i >> 6, c = (i & 63) * 4;
        *(float4*)&Bs[r][c] = *(const float4*)&wbase[(size_t)r * DI + c];
    }
    __syncthreads();
    // --- GEMM, K-split x2 ---
    const int hk = tid >> 8;
    const int t2 = tid & 255;
    const int ty = t2 >> 3;
    const int tx = t2 & 7;
    float acc[2][5];
#pragma unroll
    for (int r = 0; r < 2; ++r)
#pragma unroll
        for (int c = 0; c < 5; ++c) acc[r][c] = 0.f;
    const int kbase = hk * 128;
#pragma unroll 4
    for (int kk = 0; kk < 128; kk += 4) {
        const int k = kbase + kk;
        float4 a0 = *(float4*)&As[2 * ty][k];
        float4 a1 = *(float4*)&As[2 * ty + 1][k];
        float4 b[5];
#pragma unroll
        for (int c = 0; c < 5; ++c) b[c] = *(float4*)&Bs[5 * tx + c][k];
#pragma unroll
        for (int c = 0; c < 5; ++c) {
            acc[0][c] += a0.x * b[c].x + a0.y * b[c].y + a0.z * b[c].z + a0.w * b[c].w;
            acc[1][c] += a1.x * b[c].x + a1.y * b[c].y + a1.z * b[c].z + a1.w * b[c].w;
        }
    }
    if (hk == 0) {
#pragma unroll
        for (int r = 0; r < 2; ++r)
#pragma unroll
            for (int c = 0; c < 5; ++c) xdS[2 * ty + r][5 * tx + c] = acc[r][c];
    }
    __syncthreads();
    if (hk == 1) {
#pragma unroll
        for (int r = 0; r < 2; ++r)
#pragma unroll
            for (int c = 0; c < 5; ++c) {
                int m = 2 * ty + r, col = 5 * tx + c;
                float v = xdS[m][col] + acc[r][c];
                xdS[m][col] = v;
                xdbl[(size_t)(m0 + m) * XDBL + col] = v;
            }
    }
    __syncthreads();
    // --- delta epilogue -> dlt ---
    {
        const int ch = tid & 255;
        const int tk0 = (tid >> 8) * 32;
        float4 dw0 = *(const float4*)&dtw[((size_t)l * DI + ch) * DTR];
        float4 dw1 = *(const float4*)&dtw[((size_t)l * DI + ch) * DTR + 4];
        const float bias = dtb[l * DI + ch];
#pragma unroll 8
        for (int tk = tk0; tk < tk0 + 32; ++tk) {
            const float* xr = xdS[tk];
            float a = bias + xr[0] * dw0.x + xr[1] * dw0.y + xr[2] * dw0.z + xr[3] * dw0.w
                           + xr[4] * dw1.x + xr[5] * dw1.y + xr[6] * dw1.z + xr[7] * dw1.w;
            float sp = (a > 20.f) ? a : log1pf(__expf(a));
            dlt[(size_t)(m0 + tk) * DI + ch] = sp;
        }
    }
}

// ============ kernel 4: chunked scan pass 1 — local states + delta sums ============
__global__ __launch_bounds__(256) void k_scan1(const float* __restrict__ dlt,
                                               const float* __restrict__ u,
                                               const float* __restrict__ xdbl,
                                               const float* __restrict__ alog,
                                               float* __restrict__ hloc,
                                               float* __restrict__ Sbuf, int l) {
    const int n = blockIdx.x >> 5;
    const int c = (blockIdx.x >> 2) & 7;
    const int q = blockIdx.x & 3;
    const int tid = threadIdx.x;
    const int ch = tid >> 2, sg = tid & 3;
    const int d = q * 64 + ch;
    __shared__ float Bs[CH * DS];
    if (tid < 128) {
        int t = tid >> 2, sq = tid & 3;
        const float* row = xdbl + ((size_t)n * TT + c * CH + t) * XDBL;
        *(float4*)&Bs[t * DS + 4 * sq] = *(const float4*)&row[DTR + 4 * sq];
    }
    __syncthreads();
    float4 av = *(const float4*)&alog[((size_t)l * DI + d) * DS + sg * 4];
    float A[4] = {-__expf(av.x), -__expf(av.y), -__expf(av.z), -__expf(av.w)};
    float hst[4] = {0.f, 0.f, 0.f, 0.f};
    float S = 0.f;

    const float* dlt_p = dlt + ((size_t)n * TT + c * CH) * DI + d;
    const float* uv_p  = u + ((size_t)n * TT + c * CH) * DI + d;
    float pD[16], pU[16];
#pragma unroll
    for (int j = 0; j < 16; ++j) {
        pD[j] = dlt_p[(size_t)j * DI];
        pU[j] = uv_p[(size_t)j * DI];
    }
    for (int g = 0; g < 2; ++g) {
        float cD[16], cU[16];
#pragma unroll
        for (int j = 0; j < 16; ++j) { cD[j] = pD[j]; cU[j] = pU[j]; }
        if (g == 0) {
#pragma unroll
            for (int j = 0; j < 16; ++j) {
                pD[j] = dlt_p[(size_t)(16 + j) * DI];
                pU[j] = uv_p[(size_t)(16 + j) * DI];
            }
        }
#pragma unroll
        for (int j = 0; j < 16; ++j) {
            const int t = g * 16 + j;
            float dltv = cD[j];
            float du = dltv * cU[j];
            const float* bt = Bs + t * DS + sg * 4;
            S += dltv;
#pragma unroll
            for (int s = 0; s < 4; ++s) {
                float dA = __expf(dltv * A[s]);
                hst[s] = dA * hst[s] + du * bt[s];
            }
        }
    }
    size_t idx = ((((size_t)n * NCH + c) * 4 + q) * 256 + tid);
    float4 hv = {hst[0], hst[1], hst[2], hst[3]};
    *(float4*)&hloc[idx * 4] = hv;
    if (sg == 0) Sbuf[(((size_t)n * NCH + c) * 4 + q) * 64 + ch] = S;
}

// ============ kernel 5: chunked scan pass 2 — inline prefix + full chunk scan ======
// y written over dlt
__global__ __launch_bounds__(256) void k_scan2(float* __restrict__ dlt,
                                               const float* __restrict__ u,
                                               const float* __restrict__ xdbl,
                                               const float* __restrict__ alog,
                                               const float* __restrict__ hloc,
                                               const float* __restrict__ Sbuf, int l) {
    const int n = blockIdx.x >> 5;
    const int c = (blockIdx.x >> 2) & 7;
    const int q = blockIdx.x & 3;
    const int tid = threadIdx.x;
    const int ch = tid >> 2, sg = tid & 3;
    const int d = q * 64 + ch;
    __shared__ float Bs[CH * DS];
    __shared__ float Cs[CH * DS];
    if (tid < 128) {
        int t = tid >> 2, sq = tid & 3;
        const float* row = xdbl + ((size_t)n * TT + c * CH + t) * XDBL;
        *(float4*)&Bs[t * DS + 4 * sq] = *(const float4*)&row[DTR + 4 * sq];
        *(float4*)&Cs[t * DS + 4 * sq] = *(const float4*)&row[DTR + DS + 4 * sq];
    }
    __syncthreads();
    float4 av = *(const float4*)&alog[((size_t)l * DI + d) * DS + sg * 4];
    float A[4] = {-__expf(av.x), -__expf(av.y), -__expf(av.z), -__expf(av.w)};
    // inline prefix over chunks < c (replaces k_stitch)
    float hst[4] = {0.f, 0.f, 0.f, 0.f};
    for (int j = 0; j < c; ++j) {
        size_t idxj = ((((size_t)n * NCH + j) * 4 + q) * 256 + tid);
        float4 hl = *(const float4*)&hloc[idxj * 4];
        float S = Sbuf[(((size_t)n * NCH + j) * 4 + q) * 64 + ch];
        hst[0] = hst[0] * __expf(A[0] * S) + hl.x;
        hst[1] = hst[1] * __expf(A[1] * S) + hl.y;
        hst[2] = hst[2] * __expf(A[2] * S) + hl.z;
        hst[3] = hst[3] * __expf(A[3] * S) + hl.w;
    }

    float* dlt_p = dlt + ((size_t)n * TT + c * CH) * DI + d;   // delta in, y out
    const float* uv_p = u + ((size_t)n * TT + c * CH) * DI + d;
    float pD[16], pU[16];
#pragma unroll
    for (int j = 0; j < 16; ++j) {
        pD[j] = dlt_p[(size_t)j * DI];
        pU[j] = uv_p[(size_t)j * DI];
    }
    for (int g = 0; g < 2; ++g) {
        float cD[16], cU[16];
#pragma unroll
        for (int j = 0; j < 16; ++j) { cD[j] = pD[j]; cU[j] = pU[j]; }
        if (g == 0) {
#pragma unroll
            for (int j = 0; j < 16; ++j) {
                pD[j] = dlt_p[(size_t)(16 + j) * DI];
                pU[j] = uv_p[(size_t)(16 + j) * DI];
            }
        }
#pragma unroll
        for (int j = 0; j < 16; ++j) {
            const int t = g * 16 + j;
            float dltv = cD[j];
            float du = dltv * cU[j];
            const float* bt = Bs + t * DS + sg * 4;
            const float* ct = Cs + t * DS + sg * 4;
            float y = 0.f;
#pragma unroll
            for (int s = 0; s < 4; ++s) {
                float dA = __expf(dltv * A[s]);
                hst[s] = dA * hst[s] + du * bt[s];
                y += hst[s] * ct[s];
            }
            y += __shfl_xor(y, 1);
            y += __shfl_xor(y, 2);
            if (sg == 0)
                dlt_p[(size_t)t * DI] = y;   // raw einsum result
        }
    }
}

// ============ kernel 6: gate + out_proj GEMM + residual + layernorm ============
__global__ __launch_bounds__(256) void k_outproj_ln(const float* __restrict__ dlt,
                                                    const float* __restrict__ xz,
                                                    const float* __restrict__ u,
                                                    const float* __restrict__ Dvec,
                                                    const float* __restrict__ opw,
                                                    float* __restrict__ h,
                                                    const float* __restrict__ nw,
                                                    const float* __restrict__ nb, int l) {
    __shared__ float As[64][68];
    __shared__ float Bs[64][132];
    const int m0 = blockIdx.x * 64;
    const int tid = threadIdx.x;
    const int ty = tid >> 4, tx = tid & 15;
    const float* wbase = opw + (size_t)l * DM * DI;
    float acc[4][8];
#pragma unroll
    for (int r = 0; r < 4; ++r)
#pragma unroll
        for (int c = 0; c < 8; ++c) acc[r][c] = 0.f;

    for (int k0 = 0; k0 < DI; k0 += 64) {
        const int kq = tid & 15, r0 = tid >> 4;
        float4 dv = *(const float4*)&Dvec[l * DI + k0 + 4 * kq];
#pragma unroll
        for (int i = 0; i < 4; ++i) {
            int row = r0 + 16 * i;
            size_t m = (size_t)(m0 + row);
            float4 yv = *(const float4*)&dlt[m * DI + k0 + 4 * kq];             // y_pre
            float4 uv = *(const float4*)&u[m * DI + k0 + 4 * kq];
            float4 zv = *(const float4*)&xz[m * (2 * DI) + DI + k0 + 4 * kq];   // z
            float4 v;
            v.x = (yv.x + uv.x * dv.x) * silu(zv.x);
            v.y = (yv.y + uv.y * dv.y) * silu(zv.y);
            v.z = (yv.z + uv.z * dv.z) * silu(zv.z);
            v.w = (yv.w + uv.w * dv.w) * silu(zv.w);
            As[4 * kq + 0][row] = v.x; As[4 * kq + 1][row] = v.y;
            As[4 * kq + 2][row] = v.z; As[4 * kq + 3][row] = v.w;
        }
#pragma unroll
        for (int i = 0; i < 8; ++i) {
            int col = r0 + 16 * i;
            float4 wv = *(const float4*)&wbase[(size_t)col * DI + k0 + 4 * kq];
            Bs[4 * kq + 0][col] = wv.x; Bs[4 * kq + 1][col] = wv.y;
            Bs[4 * kq + 2][col] = wv.z; Bs[4 * kq + 3][col] = wv.w;
        }
        __syncthreads();
#pragma unroll 8
        for (int k = 0; k < 64; ++k) {
            float4 a = *(float4*)&As[k][ty * 4];
            float4 b0 = *(float4*)&Bs[k][tx * 8];
            float4 b1 = *(float4*)&Bs[k][tx * 8 + 4];
            float av[4] = {a.x, a.y, a.z, a.w};
            float bv[8] = {b0.x, b0.y, b0.z, b0.w, b1.x, b1.y, b1.z, b1.w};
#pragma unroll
            for (int r = 0; r < 4; ++r)
#pragma unroll
                for (int c = 0; c < 8; ++c) acc[r][c] += av[r] * bv[c];
        }
        __syncthreads();
    }
#pragma unroll
    for (int r = 0; r < 4; ++r) {
        int row = m0 + ty * 4 + r;
        float4 h0 = *(float4*)&h[(size_t)row * DM + tx * 8];
        float4 h1 = *(float4*)&h[(size_t)row * DM + tx * 8 + 4];
        float v[8] = {acc[r][0] + h0.x, acc[r][1] + h0.y, acc[r][2] + h0.z, acc[r][3] + h0.w,
                      acc[r][4] + h1.x, acc[r][5] + h1.y, acc[r][6] + h1.z, acc[r][7] + h1.w};
        float s = 0.f, q = 0.f;
#pragma unroll
        for (int c = 0; c < 8; ++c) { s += v[c]; q += v[c] * v[c]; }
#pragma unroll
        for (int o = 1; o < 16; o <<= 1) { s += __shfl_xor(s, o); q += __shfl_xor(q, o); }
        float mu = s * (1.f / DM);
        float var = q * (1.f / DM) - mu * mu;
        float rs = rsqrtf(var + LN_EPS);
        float4 o0, o1;
        o0.x = (v[0] - mu) * rs * nw[l * DM + tx * 8 + 0] + nb[l * DM + tx * 8 + 0];
        o0.y = (v[1] - mu) * rs * nw[l * DM + tx * 8 + 1] + nb[l * DM + tx * 8 + 1];
        o0.z = (v[2] - mu) * rs * nw[l * DM + tx * 8 + 2] + nb[l * DM + tx * 8 + 2];
        o0.w = (v[3] - mu) * rs * nw[l * DM + tx * 8 + 3] + nb[l * DM + tx * 8 + 3];
        o1.x = (v[4] - mu) * rs * nw[l * DM + tx * 8 + 4] + nb[l * DM + tx * 8 + 4];
        o1.y = (v[5] - mu) * rs * nw[l * DM + tx * 8 + 5] + nb[l * DM + tx * 8 + 5];
        o1.z = (v[6] - mu) * rs * nw[l * DM + tx * 8 + 6] + nb[l * DM + tx * 8 + 6];
        o1.w = (v[7] - mu) * rs * nw[l * DM + tx * 8 + 7] + nb[l * DM + tx * 8 + 7];
        *(float4*)&h[(size_t)row * DM + tx * 8] = o0;
        *(float4*)&h[(size_t)row * DM + tx * 8 + 4] = o1;
    }
}

// ============ kernel 7: final layernorm + mean over T (atomic-free) ============
// grid = NSEQ, block = 256 = 4 waves x 64 tokens each; LDS cross-wave reduce
__global__ __launch_bounds__(256) void k_final(const float* __restrict__ h,
                                               const float* __restrict__ ow,
                                               const float* __restrict__ ob,
                                               float* __restrict__ out) {
    const int n = blockIdx.x;
    const int wave = threadIdx.x >> 6, lane = threadIdx.x & 63;
    __shared__ float sm[512];
    const float w0 = ow[lane], w1 = ow[lane + 64];
    const float b0 = ob[lane], b1 = ob[lane + 64];
    float a0 = 0.f, a1 = 0.f;
    const int t0 = wave * 64;
#pragma unroll 4
    for (int i = 0; i < 64; ++i) {
        const float* row = h + ((size_t)n * TT + t0 + i) * DM;
        float v0 = row[lane], v1 = row[lane + 64];
        float s = v0 + v1, q = v0 * v0 + v1 * v1;
#pragma unroll
        for (int o = 1; o < 64; o <<= 1) { s += __shfl_xor(s, o); q += __shfl_xor(q, o); }
        float mu = s * (1.f / DM);
        float var = q * (1.f / DM) - mu * mu;
        float rs = rsqrtf(var + LN_EPS);
        a0 += (v0 - mu) * rs * w0 + b0;
        a1 += (v1 - mu) * rs * w1 + b1;
    }
    sm[wave * 128 + lane] = a0;
    sm[wave * 128 + 64 + lane] = a1;
    __syncthreads();
    if (threadIdx.x < 128) {
        int d = threadIdx.x;
        float s = sm[d] + sm[128 + d] + sm[256 + d] + sm[384 + d];
        out[n * DM + d] = s * (1.f / TT);
    }
}

extern "C" void kernel_launch(void* const* d_in, const int* in_sizes, int n_in,
                              void* d_out, int out_size, void* d_ws, size_t ws_size,
                              hipStream_t stream) {
    const float* x     = (const float*)d_in[0];
    const float* inp_w = (const float*)d_in[1];
    const float* inp_b = (const float*)d_in[2];
    const float* ipw   = (const float*)d_in[3];
    const float* cw    = (const float*)d_in[4];
    const float* cb    = (const float*)d_in[5];
    const float* xpw   = (const float*)d_in[6];
    const float* dtw   = (const float*)d_in[7];
    const float* dtb   = (const float*)d_in[8];
    const float* alog  = (const float*)d_in[9];
    const float* Dv    = (const float*)d_in[10];
    const float* opw   = (const float*)d_in[11];
    const float* nw    = (const float*)d_in[12];
    const float* nb    = (const float*)d_in[13];
    const float* onw   = (const float*)d_in[14];
    const float* onb   = (const float*)d_in[15];

    float* base = (float*)d_ws;
    const size_t NT = (size_t)NSEQ * TT;
    float* h    = base;                 // NT*128
    float* xz   = h + NT * DM;          // NT*512  [xi | z]  (xi stays intact)
    float* u    = xz + NT * 2 * DI;     // NT*256  conv+silu output
    float* xdbl = u + NT * DI;          // NT*40
    float* dlt  = xdbl + NT * XDBL;     // NT*256  delta in, y out
    float* hloc = dlt + NT * DI;        // NSEQ*NCH*4*256*4
    float* Sbuf = hloc + (size_t)NSEQ * NCH * 4 * 256 * 4;

    k_input_proj<<<NT / 64, 256, 0, stream>>>(x, inp_w, inp_b, h);
    for (int l = 0; l < 2; ++l) {
        k_in_proj<<<(NT / 128) * 4, 256, 0, stream>>>(h, ipw, xz, l);
        k_xd<<<NT / 64, 512, 0, stream>>>(xz, u, cw, cb, xpw, dtw, dtb, xdbl, dlt, l);
        k_scan1<<<NSEQ * 4 * NCH, 256, 0, stream>>>(dlt, u, xdbl, alog, hloc, Sbuf, l);
        k_scan2<<<NSEQ * 4 * NCH, 256, 0, stream>>>(dlt, u, xdbl, alog, hloc, Sbuf, l);
        k_outproj_ln<<<NT / 64, 256, 0, stream>>>(dlt, xz, u, Dv, opw, h, nw, nb, l);
    }
    k_final<<<NSEQ, 256, 0, stream>>>(h, onw, onb, (float*)d_out);
}